// Round 6
// baseline (271.071 us; speedup 1.0000x reference)
//
#include <hip/hip_runtime.h>

// Problem constants: N=50000 nodes, E=800000 edges, IN_F=H_F=128, OUT_F=3.
#define NN   50000
#define NE   800000
#define FH   128
#define NOUT 3
#define BN_EPS 1e-5f

#define CAP  64            // bucket capacity per node; in-deg ~ Poisson(16),
                           // P(deg>=64) ~ 1e-18/node -- safe
#define EWS  65535.0f      // 16-bit fixed-point scale for edge weights
#define IEWS (1.0f / 65535.0f)

#define GEMM_BLKS   (NN / 16)     // 3125
#define BUCKET_BLKS (NE / 256)    // 3125 exactly

// Workspace layout (float-sized slots). Total ~9.75M floats = 39 MB.
#define WS_H2     0           // h packed bf16x2, uint[NN*64]   [3200000]
#define WS_AGG2   3200000     // relu out packed bf16x2 uint[NN*64]
#define WS_BUCKET 6400000     // uint[NN*CAP] (src<<16 | ew16)  [3200000]
#define WS_CNT    9600000     // int[NN] bucket counts
#define WS_DINV   9650000     // float[NN]
#define WS_SUMS   9700000     // sum[128], sumsq[128]
#define WS_PREP   9700256     // wmod[128*3], bias_out[3]

// round-to-nearest-even bf16 packing of two floats -> uint (lo=a, hi=b)
__device__ __forceinline__ unsigned int pack_bf16(float a, float b) {
    unsigned int ua = __float_as_uint(a);
    unsigned int ub = __float_as_uint(b);
    ua += 0x7fffu + ((ua >> 16) & 1u);
    ub += 0x7fffu + ((ub >> 16) & 1u);
    return (ua >> 16) | (ub & 0xffff0000u);
}
__device__ __forceinline__ float bf16_lo(unsigned int u) {
    return __uint_as_float(u << 16);
}
__device__ __forceinline__ float bf16_hi(unsigned int u) {
    return __uint_as_float(u & 0xffff0000u);
}

#define FMA4(acc, a, w0, w1, w2, w3)                                          \
    acc.x = fmaf(a.x, w0.x, fmaf(a.y, w1.x, fmaf(a.z, w2.x, fmaf(a.w, w3.x, acc.x)))); \
    acc.y = fmaf(a.x, w0.y, fmaf(a.y, w1.y, fmaf(a.z, w2.y, fmaf(a.w, w3.y, acc.y)))); \
    acc.z = fmaf(a.x, w0.z, fmaf(a.y, w1.z, fmaf(a.z, w2.z, fmaf(a.w, w3.z, acc.z)))); \
    acc.w = fmaf(a.x, w0.w, fmaf(a.y, w1.w, fmaf(a.z, w2.w, fmaf(a.w, w3.w, acc.w))));

// ---------------------------------------------------------------------------
// K1: FUSED gemm + bucket. Blocks [0,3125) compute h=x@conv_w (bf16-packed
// out, conv_w read straight from L2 -- no LDS so bucket blocks keep full
// occupancy); blocks [3125,6250) bucket edges by destination with one u32
// atomic each. Independent work co-scheduled in one dispatch: bucket's
// atomic-latency bubbles hide under gemm's VALU work.
// ---------------------------------------------------------------------------
__global__ __launch_bounds__(256) void k_gemm_bucket(
        const float* __restrict__ x, const float* __restrict__ w,
        unsigned int* __restrict__ h2,
        const int* __restrict__ ei, const float* __restrict__ ew,
        int* __restrict__ cnt, unsigned int* __restrict__ bucket) {
    if (blockIdx.x < GEMM_BLKS) {
        const int j  = (threadIdx.x & 31) * 4;   // feature base (0..124)
        const int p  = threadIdx.x >> 5;
        const int n0 = blockIdx.x * 16 + p * 2;

        const float4* x0 = (const float4*)(x + (size_t)n0 * FH);
        const float4* x1 = (const float4*)(x + (size_t)(n0 + 1) * FH);
        float4 acc0 = {0.f, 0.f, 0.f, 0.f};
        float4 acc1 = {0.f, 0.f, 0.f, 0.f};

#pragma unroll 4
        for (int k4 = 0; k4 < FH / 4; ++k4) {
            float4 a0 = x0[k4];
            float4 a1 = x1[k4];
            const float* wr = w + (k4 * 4) * FH + j;   // 64 KB, L2-resident
            float4 w0 = *(const float4*)(wr);
            float4 w1 = *(const float4*)(wr + FH);
            float4 w2 = *(const float4*)(wr + 2 * FH);
            float4 w3 = *(const float4*)(wr + 3 * FH);
            FMA4(acc0, a0, w0, w1, w2, w3);
            FMA4(acc1, a1, w0, w1, w2, w3);
        }
        uint2 o0, o1;
        o0.x = pack_bf16(acc0.x, acc0.y);  o0.y = pack_bf16(acc0.z, acc0.w);
        o1.x = pack_bf16(acc1.x, acc1.y);  o1.y = pack_bf16(acc1.z, acc1.w);
        *(uint2*)(h2 + (size_t)n0 * 64 + (j >> 1))       = o0;
        *(uint2*)(h2 + (size_t)(n0 + 1) * 64 + (j >> 1)) = o1;
    } else {
        int e = (blockIdx.x - GEMM_BLKS) * 256 + threadIdx.x;  // < NE exactly
        int row = ei[e];
        int col = ei[NE + e];
        unsigned int fx = __float2uint_rn(ew[e] * EWS);
        int slot = atomicAdd(&cnt[col], 1);
        bucket[(size_t)col * CAP + slot] = ((unsigned int)row << 16) | fx;
    }
}

// ---------------------------------------------------------------------------
// K2: dinv[n] = rsqrt(deg_n + 1). Wave per node, lane-parallel bucket sum.
// ---------------------------------------------------------------------------
__global__ __launch_bounds__(256) void k_degdinv(const unsigned int* __restrict__ bucket,
                                                 const int* __restrict__ cnt,
                                                 float* __restrict__ dinv) {
    int n = blockIdx.x * 4 + (threadIdx.x >> 6);  // 12500 blocks exactly
    int lane = threadIdx.x & 63;
    int c = cnt[n];
    unsigned int v = (lane < c) ? (bucket[(size_t)n * CAP + lane] & 0xffffu) : 0u;
#pragma unroll
    for (int off = 32; off > 0; off >>= 1) v += __shfl_down(v, off, 64);
    if (lane == 0) {
        float deg = (float)v * IEWS;
        dinv[n] = rsqrtf(deg + 1.0f);  // +1 = self loop
    }
}

// ---------------------------------------------------------------------------
// K3: gather-aggregate. One wave per node; lane owns feature pair.
//   agg[n] = relu( dinv[n]*( sum_e h[src]*dinv[src]*ew + dinv[n]*h[n] ) + b )
// Output packed bf16.
// ---------------------------------------------------------------------------
__global__ __launch_bounds__(256) void k_gather(const unsigned int* __restrict__ h2,
                                                const float* __restrict__ dinv,
                                                const unsigned int* __restrict__ bucket,
                                                const int* __restrict__ cnt,
                                                const float* __restrict__ conv_b,
                                                unsigned int* __restrict__ agg2) {
    int n = blockIdx.x * 4 + (threadIdx.x >> 6);  // 12500 blocks exactly
    int lane = threadIdx.x & 63;

    float dvn = dinv[n];
    unsigned int hself = h2[(size_t)n * 64 + lane];
    float ax = bf16_lo(hself) * dvn;
    float ay = bf16_hi(hself) * dvn;

    const unsigned int* bkt = bucket + (size_t)n * CAP;
    int c = cnt[n];
    int j = 0;
    for (; j + 4 <= c; j += 4) {
        unsigned int u0 = bkt[j], u1 = bkt[j + 1], u2 = bkt[j + 2], u3 = bkt[j + 3];
        int s0 = u0 >> 16, s1 = u1 >> 16, s2 = u2 >> 16, s3 = u3 >> 16;
        float t0 = dinv[s0] * (float)(u0 & 0xffffu) * IEWS;
        float t1 = dinv[s1] * (float)(u1 & 0xffffu) * IEWS;
        float t2 = dinv[s2] * (float)(u2 & 0xffffu) * IEWS;
        float t3 = dinv[s3] * (float)(u3 & 0xffffu) * IEWS;
        unsigned int q0 = h2[(size_t)s0 * 64 + lane];
        unsigned int q1 = h2[(size_t)s1 * 64 + lane];
        unsigned int q2 = h2[(size_t)s2 * 64 + lane];
        unsigned int q3 = h2[(size_t)s3 * 64 + lane];
        ax = fmaf(bf16_lo(q0), t0, ax);  ay = fmaf(bf16_hi(q0), t0, ay);
        ax = fmaf(bf16_lo(q1), t1, ax);  ay = fmaf(bf16_hi(q1), t1, ay);
        ax = fmaf(bf16_lo(q2), t2, ax);  ay = fmaf(bf16_hi(q2), t2, ay);
        ax = fmaf(bf16_lo(q3), t3, ax);  ay = fmaf(bf16_hi(q3), t3, ay);
    }
    for (; j < c; ++j) {
        unsigned int u0 = bkt[j];
        int s0 = u0 >> 16;
        float t0 = dinv[s0] * (float)(u0 & 0xffffu) * IEWS;
        unsigned int q0 = h2[(size_t)s0 * 64 + lane];
        ax = fmaf(bf16_lo(q0), t0, ax);  ay = fmaf(bf16_hi(q0), t0, ay);
    }

    float2 bv = *(const float2*)(conv_b + lane * 2);
    float ox = fmaxf(fmaf(dvn, ax, bv.x), 0.f);
    float oy = fmaxf(fmaf(dvn, ay, bv.y), 0.f);
    agg2[(size_t)n * 64 + lane] = pack_bf16(ox, oy);
}

// ---------------------------------------------------------------------------
// K4: BN stats — per-feature sum/sumsq of agg2 (bf16-packed, already relu'd)
// ---------------------------------------------------------------------------
__global__ __launch_bounds__(256) void k_stats(const unsigned int* __restrict__ agg2,
                                               float* __restrict__ sums) {
    int u = threadIdx.x & 63;   // uint column -> features 2u, 2u+1
    int q = threadIdx.x >> 6;   // 0..3
    float sl = 0.f, s2l = 0.f, sh = 0.f, s2h = 0.f;
    for (int n = blockIdx.x * 4 + q; n < NN; n += gridDim.x * 4) {
        unsigned int v = agg2[(size_t)n * 64 + u];
        float a = bf16_lo(v), b = bf16_hi(v);
        sl += a;  s2l = fmaf(a, a, s2l);
        sh += b;  s2h = fmaf(b, b, s2h);
    }
    __shared__ float red[256];
    float vals[4] = {sl, sh, s2l, s2h};
    // sums layout: [0..127]=sum, [128..255]=sumsq; feature = 2u (+1 for hi)
    int dst[4] = {2 * u, 2 * u + 1, FH + 2 * u, FH + 2 * u + 1};
#pragma unroll
    for (int r = 0; r < 4; ++r) {
        red[threadIdx.x] = vals[r];
        __syncthreads();
        if (q == 0)
            atomicAdd(&sums[dst[r]],
                      red[u] + red[u + 64] + red[u + 128] + red[u + 192]);
        __syncthreads();
    }
}

// ---------------------------------------------------------------------------
// K5: fold BN affine into the final linear.
// ---------------------------------------------------------------------------
__global__ void k_prep(const float* __restrict__ sums,
                       const float* __restrict__ gamma,
                       const float* __restrict__ beta,
                       const float* __restrict__ lin_w,
                       const float* __restrict__ lin_b,
                       float* __restrict__ prep) {
    __shared__ float red[3 * FH];
    int f = threadIdx.x;  // 128 threads
    float mean = sums[f] * (1.0f / NN);
    float var  = sums[FH + f] * (1.0f / NN) - mean * mean;
    float inv  = rsqrtf(var + BN_EPS);
    float sc   = inv * gamma[f];
    float sh   = fmaf(-mean, sc, beta[f]);
#pragma unroll
    for (int o = 0; o < NOUT; ++o) {
        float lw = lin_w[f * NOUT + o];
        prep[f * NOUT + o] = sc * lw;
        red[o * FH + f]    = sh * lw;
    }
    __syncthreads();
    if (f < NOUT) {
        float s = lin_b[f];
        for (int i = 0; i < FH; ++i) s += red[f * FH + i];
        prep[3 * FH + f] = s;
    }
}

// ---------------------------------------------------------------------------
// K6: out[n][o] = sum_f agg[n][f] * wmod[f][o] + bias_out[o]
// ---------------------------------------------------------------------------
__global__ __launch_bounds__(256) void k_final(const unsigned int* __restrict__ agg2,
                                               const float* __restrict__ prep,
                                               float* __restrict__ out) {
    int n = blockIdx.x * 4 + (threadIdx.x >> 6);
    int lane = threadIdx.x & 63;
    int f0 = lane * 2, f1 = lane * 2 + 1;

    unsigned int v = agg2[(size_t)n * 64 + lane];
    float vx = bf16_lo(v), vy = bf16_hi(v);

    float o0 = vx * prep[f0 * NOUT + 0] + vy * prep[f1 * NOUT + 0];
    float o1 = vx * prep[f0 * NOUT + 1] + vy * prep[f1 * NOUT + 1];
    float o2 = vx * prep[f0 * NOUT + 2] + vy * prep[f1 * NOUT + 2];

#pragma unroll
    for (int off = 32; off > 0; off >>= 1) {
        o0 += __shfl_down(o0, off, 64);
        o1 += __shfl_down(o1, off, 64);
        o2 += __shfl_down(o2, off, 64);
    }
    if (lane == 0) {
        out[n * NOUT + 0] = o0 + prep[3 * FH + 0];
        out[n * NOUT + 1] = o1 + prep[3 * FH + 1];
        out[n * NOUT + 2] = o2 + prep[3 * FH + 2];
    }
}

// ---------------------------------------------------------------------------
extern "C" void kernel_launch(void* const* d_in, const int* in_sizes, int n_in,
                              void* d_out, int out_size, void* d_ws, size_t ws_size,
                              hipStream_t stream) {
    const float* x      = (const float*)d_in[0];
    const int*   ei     = (const int*)d_in[1];   // [2][NE] int32
    const float* ew     = (const float*)d_in[2];
    const float* conv_w = (const float*)d_in[3];
    const float* conv_b = (const float*)d_in[4];
    const float* gamma  = (const float*)d_in[5];
    const float* beta   = (const float*)d_in[6];
    const float* lin_w  = (const float*)d_in[7];
    const float* lin_b  = (const float*)d_in[8];
    float* out = (float*)d_out;
    float* ws  = (float*)d_ws;

    unsigned int* h2     = (unsigned int*)(ws + WS_H2);
    unsigned int* agg2   = (unsigned int*)(ws + WS_AGG2);
    unsigned int* bucket = (unsigned int*)(ws + WS_BUCKET);
    int*          cnt    = (int*)(ws + WS_CNT);
    float*        dinv   = ws + WS_DINV;
    float*        sums   = ws + WS_SUMS;
    float*        prep   = ws + WS_PREP;

    // ws is poisoned 0xAA before every launch — zero the accumulators.
    hipMemsetAsync(cnt,  0, (size_t)NN * sizeof(int), stream);
    hipMemsetAsync(sums, 0, 2 * FH * sizeof(float), stream);

    k_gemm_bucket<<<GEMM_BLKS + BUCKET_BLKS, 256, 0, stream>>>(
        x, conv_w, h2, ei, ew, cnt, bucket);
    k_degdinv<<<NN / 4, 256, 0, stream>>>(bucket, cnt, dinv);
    k_gather <<<NN / 4, 256, 0, stream>>>(h2, dinv, bucket, cnt, conv_b, agg2);
    k_stats  <<<512,    256, 0, stream>>>(agg2, sums);
    k_prep   <<<1,      FH,  0, stream>>>(sums, gamma, beta, lin_w, lin_b, prep);
    k_final  <<<NN / 4, 256, 0, stream>>>(agg2, prep, out);
}

// Round 7
// 242.786 us; speedup vs baseline: 1.1165x; 1.1165x over previous
//
#include <hip/hip_runtime.h>

// Problem constants: N=50000 nodes, E=800000 edges, IN_F=H_F=128, OUT_F=3.
#define NN   50000
#define NE   800000
#define FH   128
#define NOUT 3
#define BN_EPS 1e-5f

#define CAP  64            // bucket capacity per node; in-deg ~ Poisson(16),
                           // P(deg>=64) ~ 1e-18/node -- safe
#define EWS  65535.0f      // 16-bit fixed-point scale for edge weights
#define IEWS (1.0f / 65535.0f)

#define GEMM_BLKS   (NN / 16)     // 3125
#define BUCKET_BLKS (NE / 256)    // 3125 exactly

// Workspace layout (float-sized slots). Total ~9.75M floats = 39 MB.
#define WS_H2     0           // h packed bf16x2, uint[NN*64]   [3200000]
#define WS_AGG2   3200000     // relu out packed bf16x2 uint[NN*64]
#define WS_BUCKET 6400000     // uint[NN*CAP] (src<<16 | ew16)  [3200000]
#define WS_CNT    9600000     // int[NN] bucket counts
#define WS_DINV   9650000     // float[NN]
#define WS_SUMS   9700000     // sum[128], sumsq[128]
#define WS_PREP   9700256     // wmod[128*3], bias_out[3]

// round-to-nearest-even bf16 packing of two floats -> uint (lo=a, hi=b)
__device__ __forceinline__ unsigned int pack_bf16(float a, float b) {
    unsigned int ua = __float_as_uint(a);
    unsigned int ub = __float_as_uint(b);
    ua += 0x7fffu + ((ua >> 16) & 1u);
    ub += 0x7fffu + ((ub >> 16) & 1u);
    return (ua >> 16) | (ub & 0xffff0000u);
}
__device__ __forceinline__ float bf16_lo(unsigned int u) {
    return __uint_as_float(u << 16);
}
__device__ __forceinline__ float bf16_hi(unsigned int u) {
    return __uint_as_float(u & 0xffff0000u);
}

#define FMA4(acc, a, w0, w1, w2, w3)                                          \
    acc.x = fmaf(a.x, w0.x, fmaf(a.y, w1.x, fmaf(a.z, w2.x, fmaf(a.w, w3.x, acc.x)))); \
    acc.y = fmaf(a.x, w0.y, fmaf(a.y, w1.y, fmaf(a.z, w2.y, fmaf(a.w, w3.y, acc.y)))); \
    acc.z = fmaf(a.x, w0.z, fmaf(a.y, w1.z, fmaf(a.z, w2.z, fmaf(a.w, w3.z, acc.z)))); \
    acc.w = fmaf(a.x, w0.w, fmaf(a.y, w1.w, fmaf(a.z, w2.w, fmaf(a.w, w3.w, acc.w))));

// ---------------------------------------------------------------------------
// K1: FUSED gemm + bucket, INTERLEAVED block mapping (even blk -> gemm, odd
// -> bucket) so both types are co-resident per CU: bucket's atomic-latency
// bubbles hide under gemm's VALU work. Gemm stages conv_w in 4x 32-row LDS
// chunks (16 KB -- 8 blocks/CU still fit: 128 KB <= 160 KB, so bucket
// occupancy is not throttled, unlike a 64 KB allocation).
// ---------------------------------------------------------------------------
__global__ __launch_bounds__(256) void k_gemm_bucket(
        const float* __restrict__ x, const float* __restrict__ w,
        unsigned int* __restrict__ h2,
        const int* __restrict__ ei, const float* __restrict__ ew,
        int* __restrict__ cnt, unsigned int* __restrict__ bucket) {
    __shared__ float sw[32 * FH];  // 16 KB
    if ((blockIdx.x & 1) == 0) {
        const int gblk = blockIdx.x >> 1;        // 0..3124
        const int j  = (threadIdx.x & 31) * 4;   // feature base (0..124)
        const int p  = threadIdx.x >> 5;
        const int n0 = gblk * 16 + p * 2;

        const float4* x0 = (const float4*)(x + (size_t)n0 * FH);
        const float4* x1 = (const float4*)(x + (size_t)(n0 + 1) * FH);
        float4 acc0 = {0.f, 0.f, 0.f, 0.f};
        float4 acc1 = {0.f, 0.f, 0.f, 0.f};

        for (int c = 0; c < 4; ++c) {
            // stage w rows [32c, 32c+32): 1024 float4 across 256 threads
            const float4* w4 = (const float4*)(w + (size_t)c * 32 * FH);
            float4* s4 = (float4*)sw;
#pragma unroll
            for (int i = 0; i < 4; ++i)
                s4[threadIdx.x + i * 256] = w4[threadIdx.x + i * 256];
            __syncthreads();
#pragma unroll
            for (int k4 = 0; k4 < 8; ++k4) {
                float4 a0 = x0[c * 8 + k4];
                float4 a1 = x1[c * 8 + k4];
                const float* wr = &sw[(k4 * 4) * FH + j];
                float4 w0 = *(const float4*)(wr);
                float4 w1 = *(const float4*)(wr + FH);
                float4 w2 = *(const float4*)(wr + 2 * FH);
                float4 w3 = *(const float4*)(wr + 3 * FH);
                FMA4(acc0, a0, w0, w1, w2, w3);
                FMA4(acc1, a1, w0, w1, w2, w3);
            }
            __syncthreads();
        }
        uint2 o0, o1;
        o0.x = pack_bf16(acc0.x, acc0.y);  o0.y = pack_bf16(acc0.z, acc0.w);
        o1.x = pack_bf16(acc1.x, acc1.y);  o1.y = pack_bf16(acc1.z, acc1.w);
        *(uint2*)(h2 + (size_t)n0 * 64 + (j >> 1))       = o0;
        *(uint2*)(h2 + (size_t)(n0 + 1) * 64 + (j >> 1)) = o1;
    } else {
        int e = (blockIdx.x >> 1) * 256 + threadIdx.x;  // < NE exactly
        int row = ei[e];
        int col = ei[NE + e];
        unsigned int fx = __float2uint_rn(ew[e] * EWS);
        int slot = atomicAdd(&cnt[col], 1);
        bucket[(size_t)col * CAP + slot] = ((unsigned int)row << 16) | fx;
    }
}

// ---------------------------------------------------------------------------
// K2: dinv[n] = rsqrt(deg_n + 1). Wave per node, lane-parallel bucket sum.
// ---------------------------------------------------------------------------
__global__ __launch_bounds__(256) void k_degdinv(const unsigned int* __restrict__ bucket,
                                                 const int* __restrict__ cnt,
                                                 float* __restrict__ dinv) {
    int n = blockIdx.x * 4 + (threadIdx.x >> 6);  // 12500 blocks exactly
    int lane = threadIdx.x & 63;
    int c = cnt[n];
    unsigned int v = (lane < c) ? (bucket[(size_t)n * CAP + lane] & 0xffffu) : 0u;
#pragma unroll
    for (int off = 32; off > 0; off >>= 1) v += __shfl_down(v, off, 64);
    if (lane == 0) {
        float deg = (float)v * IEWS;
        dinv[n] = rsqrtf(deg + 1.0f);  // +1 = self loop
    }
}

// ---------------------------------------------------------------------------
// K3: gather-aggregate. One wave per node; lane owns feature pair.
//   agg[n] = relu( dinv[n]*( sum_e h[src]*dinv[src]*ew + dinv[n]*h[n] ) + b )
// Output packed bf16.
// ---------------------------------------------------------------------------
__global__ __launch_bounds__(256) void k_gather(const unsigned int* __restrict__ h2,
                                                const float* __restrict__ dinv,
                                                const unsigned int* __restrict__ bucket,
                                                const int* __restrict__ cnt,
                                                const float* __restrict__ conv_b,
                                                unsigned int* __restrict__ agg2) {
    int n = blockIdx.x * 4 + (threadIdx.x >> 6);  // 12500 blocks exactly
    int lane = threadIdx.x & 63;

    float dvn = dinv[n];
    unsigned int hself = h2[(size_t)n * 64 + lane];
    float ax = bf16_lo(hself) * dvn;
    float ay = bf16_hi(hself) * dvn;

    const unsigned int* bkt = bucket + (size_t)n * CAP;
    int c = cnt[n];
    int j = 0;
    for (; j + 4 <= c; j += 4) {
        unsigned int u0 = bkt[j], u1 = bkt[j + 1], u2 = bkt[j + 2], u3 = bkt[j + 3];
        int s0 = u0 >> 16, s1 = u1 >> 16, s2 = u2 >> 16, s3 = u3 >> 16;
        float t0 = dinv[s0] * (float)(u0 & 0xffffu) * IEWS;
        float t1 = dinv[s1] * (float)(u1 & 0xffffu) * IEWS;
        float t2 = dinv[s2] * (float)(u2 & 0xffffu) * IEWS;
        float t3 = dinv[s3] * (float)(u3 & 0xffffu) * IEWS;
        unsigned int q0 = h2[(size_t)s0 * 64 + lane];
        unsigned int q1 = h2[(size_t)s1 * 64 + lane];
        unsigned int q2 = h2[(size_t)s2 * 64 + lane];
        unsigned int q3 = h2[(size_t)s3 * 64 + lane];
        ax = fmaf(bf16_lo(q0), t0, ax);  ay = fmaf(bf16_hi(q0), t0, ay);
        ax = fmaf(bf16_lo(q1), t1, ax);  ay = fmaf(bf16_hi(q1), t1, ay);
        ax = fmaf(bf16_lo(q2), t2, ax);  ay = fmaf(bf16_hi(q2), t2, ay);
        ax = fmaf(bf16_lo(q3), t3, ax);  ay = fmaf(bf16_hi(q3), t3, ay);
    }
    for (; j < c; ++j) {
        unsigned int u0 = bkt[j];
        int s0 = u0 >> 16;
        float t0 = dinv[s0] * (float)(u0 & 0xffffu) * IEWS;
        unsigned int q0 = h2[(size_t)s0 * 64 + lane];
        ax = fmaf(bf16_lo(q0), t0, ax);  ay = fmaf(bf16_hi(q0), t0, ay);
    }

    float2 bv = *(const float2*)(conv_b + lane * 2);
    float ox = fmaxf(fmaf(dvn, ax, bv.x), 0.f);
    float oy = fmaxf(fmaf(dvn, ay, bv.y), 0.f);
    agg2[(size_t)n * 64 + lane] = pack_bf16(ox, oy);
}

// ---------------------------------------------------------------------------
// K4: BN stats — per-feature sum/sumsq of agg2 (bf16-packed, already relu'd)
// ---------------------------------------------------------------------------
__global__ __launch_bounds__(256) void k_stats(const unsigned int* __restrict__ agg2,
                                               float* __restrict__ sums) {
    int u = threadIdx.x & 63;   // uint column -> features 2u, 2u+1
    int q = threadIdx.x >> 6;   // 0..3
    float sl = 0.f, s2l = 0.f, sh = 0.f, s2h = 0.f;
    for (int n = blockIdx.x * 4 + q; n < NN; n += gridDim.x * 4) {
        unsigned int v = agg2[(size_t)n * 64 + u];
        float a = bf16_lo(v), b = bf16_hi(v);
        sl += a;  s2l = fmaf(a, a, s2l);
        sh += b;  s2h = fmaf(b, b, s2h);
    }
    __shared__ float red[256];
    float vals[4] = {sl, sh, s2l, s2h};
    int dst[4] = {2 * u, 2 * u + 1, FH + 2 * u, FH + 2 * u + 1};
#pragma unroll
    for (int r = 0; r < 4; ++r) {
        red[threadIdx.x] = vals[r];
        __syncthreads();
        if (q == 0)
            atomicAdd(&sums[dst[r]],
                      red[u] + red[u + 64] + red[u + 128] + red[u + 192]);
        __syncthreads();
    }
}

// ---------------------------------------------------------------------------
// K5: fold BN affine into the final linear.
// ---------------------------------------------------------------------------
__global__ void k_prep(const float* __restrict__ sums,
                       const float* __restrict__ gamma,
                       const float* __restrict__ beta,
                       const float* __restrict__ lin_w,
                       const float* __restrict__ lin_b,
                       float* __restrict__ prep) {
    __shared__ float red[3 * FH];
    int f = threadIdx.x;  // 128 threads
    float mean = sums[f] * (1.0f / NN);
    float var  = sums[FH + f] * (1.0f / NN) - mean * mean;
    float inv  = rsqrtf(var + BN_EPS);
    float sc   = inv * gamma[f];
    float sh   = fmaf(-mean, sc, beta[f]);
#pragma unroll
    for (int o = 0; o < NOUT; ++o) {
        float lw = lin_w[f * NOUT + o];
        prep[f * NOUT + o] = sc * lw;
        red[o * FH + f]    = sh * lw;
    }
    __syncthreads();
    if (f < NOUT) {
        float s = lin_b[f];
        for (int i = 0; i < FH; ++i) s += red[f * FH + i];
        prep[3 * FH + f] = s;
    }
}

// ---------------------------------------------------------------------------
// K6: out[n][o] = sum_f agg[n][f] * wmod[f][o] + bias_out[o]
// ---------------------------------------------------------------------------
__global__ __launch_bounds__(256) void k_final(const unsigned int* __restrict__ agg2,
                                               const float* __restrict__ prep,
                                               float* __restrict__ out) {
    int n = blockIdx.x * 4 + (threadIdx.x >> 6);
    int lane = threadIdx.x & 63;
    int f0 = lane * 2, f1 = lane * 2 + 1;

    unsigned int v = agg2[(size_t)n * 64 + lane];
    float vx = bf16_lo(v), vy = bf16_hi(v);

    float o0 = vx * prep[f0 * NOUT + 0] + vy * prep[f1 * NOUT + 0];
    float o1 = vx * prep[f0 * NOUT + 1] + vy * prep[f1 * NOUT + 1];
    float o2 = vx * prep[f0 * NOUT + 2] + vy * prep[f1 * NOUT + 2];

#pragma unroll
    for (int off = 32; off > 0; off >>= 1) {
        o0 += __shfl_down(o0, off, 64);
        o1 += __shfl_down(o1, off, 64);
        o2 += __shfl_down(o2, off, 64);
    }
    if (lane == 0) {
        out[n * NOUT + 0] = o0 + prep[3 * FH + 0];
        out[n * NOUT + 1] = o1 + prep[3 * FH + 1];
        out[n * NOUT + 2] = o2 + prep[3 * FH + 2];
    }
}

// ---------------------------------------------------------------------------
extern "C" void kernel_launch(void* const* d_in, const int* in_sizes, int n_in,
                              void* d_out, int out_size, void* d_ws, size_t ws_size,
                              hipStream_t stream) {
    const float* x      = (const float*)d_in[0];
    const int*   ei     = (const int*)d_in[1];   // [2][NE] int32
    const float* ew     = (const float*)d_in[2];
    const float* conv_w = (const float*)d_in[3];
    const float* conv_b = (const float*)d_in[4];
    const float* gamma  = (const float*)d_in[5];
    const float* beta   = (const float*)d_in[6];
    const float* lin_w  = (const float*)d_in[7];
    const float* lin_b  = (const float*)d_in[8];
    float* out = (float*)d_out;
    float* ws  = (float*)d_ws;

    unsigned int* h2     = (unsigned int*)(ws + WS_H2);
    unsigned int* agg2   = (unsigned int*)(ws + WS_AGG2);
    unsigned int* bucket = (unsigned int*)(ws + WS_BUCKET);
    int*          cnt    = (int*)(ws + WS_CNT);
    float*        dinv   = ws + WS_DINV;
    float*        sums   = ws + WS_SUMS;
    float*        prep   = ws + WS_PREP;

    // ws is poisoned 0xAA before every launch — zero the accumulators.
    hipMemsetAsync(cnt,  0, (size_t)NN * sizeof(int), stream);
    hipMemsetAsync(sums, 0, 2 * FH * sizeof(float), stream);

    k_gemm_bucket<<<GEMM_BLKS + BUCKET_BLKS, 256, 0, stream>>>(
        x, conv_w, h2, ei, ew, cnt, bucket);
    k_degdinv<<<NN / 4, 256, 0, stream>>>(bucket, cnt, dinv);
    k_gather <<<NN / 4, 256, 0, stream>>>(h2, dinv, bucket, cnt, conv_b, agg2);
    k_stats  <<<512,    256, 0, stream>>>(agg2, sums);
    k_prep   <<<1,      FH,  0, stream>>>(sums, gamma, beta, lin_w, lin_b, prep);
    k_final  <<<NN / 4, 256, 0, stream>>>(agg2, prep, out);
}

// Round 8
// 229.142 us; speedup vs baseline: 1.1830x; 1.0595x over previous
//
#include <hip/hip_runtime.h>

// Problem constants: N=50000 nodes, E=800000 edges, IN_F=H_F=128, OUT_F=3.
#define NN   50000
#define NE   800000
#define FH   128
#define NOUT 3
#define BN_EPS 1e-5f

#define CAP  64            // bucket capacity per node; in-deg ~ Poisson(16),
                           // P(deg>=64) ~ 1e-18/node -- safe
#define EWS  65535.0f      // 16-bit fixed-point scale for edge weights
#define IEWS (1.0f / 65535.0f)

#define GEMM_BLKS   3125          // NN/16
#define BUCKET_BLKS 625           // x 256 thr x 5 edges = 800000 exactly
#define FUSED_BLKS  3750          // 6 of which every 6th (%6==5) is bucket

// Workspace layout (float-sized slots). Total ~9.75M floats = 39 MB.
#define WS_H2     0           // h packed bf16x2, uint[NN*64]   [3200000]
#define WS_AGG2   3200000     // relu out packed bf16x2 uint[NN*64]
#define WS_BUCKET 6400000     // uint[NN*CAP] (src<<16 | ew16)  [3200000]
#define WS_CNT    9600000     // int[NN] bucket counts
#define WS_DINV   9650000     // float[NN]
#define WS_SUMS   9700000     // sum[128], sumsq[128]
#define WS_PREP   9700256     // wmod[128*3], bias_out[3]

// round-to-nearest-even bf16 packing of two floats -> uint (lo=a, hi=b)
__device__ __forceinline__ unsigned int pack_bf16(float a, float b) {
    unsigned int ua = __float_as_uint(a);
    unsigned int ub = __float_as_uint(b);
    ua += 0x7fffu + ((ua >> 16) & 1u);
    ub += 0x7fffu + ((ub >> 16) & 1u);
    return (ua >> 16) | (ub & 0xffff0000u);
}
__device__ __forceinline__ float bf16_lo(unsigned int u) {
    return __uint_as_float(u << 16);
}
__device__ __forceinline__ float bf16_hi(unsigned int u) {
    return __uint_as_float(u & 0xffff0000u);
}

#define FMA4(acc, a, w0, w1, w2, w3)                                          \
    acc.x = fmaf(a.x, w0.x, fmaf(a.y, w1.x, fmaf(a.z, w2.x, fmaf(a.w, w3.x, acc.x)))); \
    acc.y = fmaf(a.x, w0.y, fmaf(a.y, w1.y, fmaf(a.z, w2.y, fmaf(a.w, w3.y, acc.y)))); \
    acc.z = fmaf(a.x, w0.z, fmaf(a.y, w1.z, fmaf(a.z, w2.z, fmaf(a.w, w3.z, acc.z)))); \
    acc.w = fmaf(a.x, w0.w, fmaf(a.y, w1.w, fmaf(a.z, w2.w, fmaf(a.w, w3.w, acc.w))));

// ---------------------------------------------------------------------------
// K1: FUSED gemm + bucket, interleaved (blockIdx%6==5 -> bucket). Bucket
// threads batch 5 edges in separated phases (loads, then 5 INDEPENDENT
// atomics, then stores) so one wave-slot amortizes 5 atomic round-trips.
// Gemm stages conv_w in 4x 32-row LDS chunks (16 KB, 8 blocks/CU OK).
// ---------------------------------------------------------------------------
__global__ __launch_bounds__(256) void k_gemm_bucket(
        const float* __restrict__ x, const float* __restrict__ w,
        unsigned int* __restrict__ h2,
        const int* __restrict__ ei, const float* __restrict__ ew,
        int* __restrict__ cnt, unsigned int* __restrict__ bucket) {
    __shared__ float sw[32 * FH];  // 16 KB
    if ((blockIdx.x % 6) != 5) {
        const int gblk = blockIdx.x - blockIdx.x / 6;  // 0..3124
        const int j  = (threadIdx.x & 31) * 4;         // feature base
        const int p  = threadIdx.x >> 5;
        const int n0 = gblk * 16 + p * 2;

        const float4* x0 = (const float4*)(x + (size_t)n0 * FH);
        const float4* x1 = (const float4*)(x + (size_t)(n0 + 1) * FH);
        float4 acc0 = {0.f, 0.f, 0.f, 0.f};
        float4 acc1 = {0.f, 0.f, 0.f, 0.f};

        for (int c = 0; c < 4; ++c) {
            const float4* w4 = (const float4*)(w + (size_t)c * 32 * FH);
            float4* s4 = (float4*)sw;
#pragma unroll
            for (int i = 0; i < 4; ++i)
                s4[threadIdx.x + i * 256] = w4[threadIdx.x + i * 256];
            __syncthreads();
#pragma unroll
            for (int k4 = 0; k4 < 8; ++k4) {
                float4 a0 = x0[c * 8 + k4];
                float4 a1 = x1[c * 8 + k4];
                const float* wr = &sw[(k4 * 4) * FH + j];
                float4 w0 = *(const float4*)(wr);
                float4 w1 = *(const float4*)(wr + FH);
                float4 w2 = *(const float4*)(wr + 2 * FH);
                float4 w3 = *(const float4*)(wr + 3 * FH);
                FMA4(acc0, a0, w0, w1, w2, w3);
                FMA4(acc1, a1, w0, w1, w2, w3);
            }
            __syncthreads();
        }
        uint2 o0, o1;
        o0.x = pack_bf16(acc0.x, acc0.y);  o0.y = pack_bf16(acc0.z, acc0.w);
        o1.x = pack_bf16(acc1.x, acc1.y);  o1.y = pack_bf16(acc1.z, acc1.w);
        *(uint2*)(h2 + (size_t)n0 * 64 + (j >> 1))       = o0;
        *(uint2*)(h2 + (size_t)(n0 + 1) * 64 + (j >> 1)) = o1;
    } else {
        const int bidx = blockIdx.x / 6;                   // 0..624
        const int e0   = bidx * 1280 + threadIdx.x;        // +k*256, k<5
        int          row[5];
        int          col[5];
        unsigned int ent[5];
        // phase 1: coalesced loads for 5 edges
#pragma unroll
        for (int k = 0; k < 5; ++k) {
            int e  = e0 + k * 256;
            row[k] = ei[e];
            col[k] = ei[NE + e];
            ent[k] = ((unsigned int)row[k] << 16) |
                     __float2uint_rn(ew[e] * EWS);
        }
        // phase 2: 5 independent atomics (issue together, drain in order)
        int slot[5];
#pragma unroll
        for (int k = 0; k < 5; ++k) slot[k] = atomicAdd(&cnt[col[k]], 1);
        // phase 3: dependent scattered stores
#pragma unroll
        for (int k = 0; k < 5; ++k)
            bucket[(size_t)col[k] * CAP + slot[k]] = ent[k];
    }
}

// ---------------------------------------------------------------------------
// K2: dinv[n] = rsqrt(deg_n + 1). Wave per node, lane-parallel bucket sum.
// ---------------------------------------------------------------------------
__global__ __launch_bounds__(256) void k_degdinv(const unsigned int* __restrict__ bucket,
                                                 const int* __restrict__ cnt,
                                                 float* __restrict__ dinv) {
    int n = blockIdx.x * 4 + (threadIdx.x >> 6);  // 12500 blocks exactly
    int lane = threadIdx.x & 63;
    int c = cnt[n];
    unsigned int v = (lane < c) ? (bucket[(size_t)n * CAP + lane] & 0xffffu) : 0u;
#pragma unroll
    for (int off = 32; off > 0; off >>= 1) v += __shfl_down(v, off, 64);
    if (lane == 0) {
        float deg = (float)v * IEWS;
        dinv[n] = rsqrtf(deg + 1.0f);  // +1 = self loop
    }
}

// ---------------------------------------------------------------------------
// K3: gather-aggregate. One wave per node; lane owns feature pair.
// uint4 bucket loads + 8-wide unroll => 8 outstanding h2 row loads.
// ---------------------------------------------------------------------------
__global__ __launch_bounds__(256) void k_gather(const unsigned int* __restrict__ h2,
                                                const float* __restrict__ dinv,
                                                const unsigned int* __restrict__ bucket,
                                                const int* __restrict__ cnt,
                                                const float* __restrict__ conv_b,
                                                unsigned int* __restrict__ agg2) {
    int n = blockIdx.x * 4 + (threadIdx.x >> 6);  // 12500 blocks exactly
    int lane = threadIdx.x & 63;

    float dvn = dinv[n];
    unsigned int hself = h2[(size_t)n * 64 + lane];
    float ax = bf16_lo(hself) * dvn;
    float ay = bf16_hi(hself) * dvn;

    const unsigned int* bkt = bucket + (size_t)n * CAP;
    int c = cnt[n];
    int j = 0;
    for (; j + 8 <= c; j += 8) {
        uint4 b0 = *(const uint4*)(bkt + j);
        uint4 b1 = *(const uint4*)(bkt + j + 4);
        unsigned int u[8] = {b0.x, b0.y, b0.z, b0.w, b1.x, b1.y, b1.z, b1.w};
        float t[8];
        unsigned int q[8];
#pragma unroll
        for (int r = 0; r < 8; ++r) {
            int s = u[r] >> 16;
            t[r] = dinv[s] * (float)(u[r] & 0xffffu) * IEWS;
            q[r] = h2[(size_t)s * 64 + lane];
        }
#pragma unroll
        for (int r = 0; r < 8; ++r) {
            ax = fmaf(bf16_lo(q[r]), t[r], ax);
            ay = fmaf(bf16_hi(q[r]), t[r], ay);
        }
    }
    if (j + 4 <= c) {
        uint4 b0 = *(const uint4*)(bkt + j);
        unsigned int u[4] = {b0.x, b0.y, b0.z, b0.w};
#pragma unroll
        for (int r = 0; r < 4; ++r) {
            int s = u[r] >> 16;
            float t = dinv[s] * (float)(u[r] & 0xffffu) * IEWS;
            unsigned int q = h2[(size_t)s * 64 + lane];
            ax = fmaf(bf16_lo(q), t, ax);
            ay = fmaf(bf16_hi(q), t, ay);
        }
        j += 4;
    }
    for (; j < c; ++j) {
        unsigned int u0 = bkt[j];
        int s0 = u0 >> 16;
        float t0 = dinv[s0] * (float)(u0 & 0xffffu) * IEWS;
        unsigned int q0 = h2[(size_t)s0 * 64 + lane];
        ax = fmaf(bf16_lo(q0), t0, ax);  ay = fmaf(bf16_hi(q0), t0, ay);
    }

    float2 bv = *(const float2*)(conv_b + lane * 2);
    float ox = fmaxf(fmaf(dvn, ax, bv.x), 0.f);
    float oy = fmaxf(fmaf(dvn, ay, bv.y), 0.f);
    agg2[(size_t)n * 64 + lane] = pack_bf16(ox, oy);
}

// ---------------------------------------------------------------------------
// K4: BN stats — per-feature sum/sumsq of agg2 (bf16-packed, already relu'd)
// ---------------------------------------------------------------------------
__global__ __launch_bounds__(256) void k_stats(const unsigned int* __restrict__ agg2,
                                               float* __restrict__ sums) {
    int u = threadIdx.x & 63;   // uint column -> features 2u, 2u+1
    int q = threadIdx.x >> 6;   // 0..3
    float sl = 0.f, s2l = 0.f, sh = 0.f, s2h = 0.f;
    for (int n = blockIdx.x * 4 + q; n < NN; n += gridDim.x * 4) {
        unsigned int v = agg2[(size_t)n * 64 + u];
        float a = bf16_lo(v), b = bf16_hi(v);
        sl += a;  s2l = fmaf(a, a, s2l);
        sh += b;  s2h = fmaf(b, b, s2h);
    }
    __shared__ float red[256];
    float vals[4] = {sl, sh, s2l, s2h};
    int dst[4] = {2 * u, 2 * u + 1, FH + 2 * u, FH + 2 * u + 1};
#pragma unroll
    for (int r = 0; r < 4; ++r) {
        red[threadIdx.x] = vals[r];
        __syncthreads();
        if (q == 0)
            atomicAdd(&sums[dst[r]],
                      red[u] + red[u + 64] + red[u + 128] + red[u + 192]);
        __syncthreads();
    }
}

// ---------------------------------------------------------------------------
// K5: fold BN affine into the final linear.
// ---------------------------------------------------------------------------
__global__ void k_prep(const float* __restrict__ sums,
                       const float* __restrict__ gamma,
                       const float* __restrict__ beta,
                       const float* __restrict__ lin_w,
                       const float* __restrict__ lin_b,
                       float* __restrict__ prep) {
    __shared__ float red[3 * FH];
    int f = threadIdx.x;  // 128 threads
    float mean = sums[f] * (1.0f / NN);
    float var  = sums[FH + f] * (1.0f / NN) - mean * mean;
    float inv  = rsqrtf(var + BN_EPS);
    float sc   = inv * gamma[f];
    float sh   = fmaf(-mean, sc, beta[f]);
#pragma unroll
    for (int o = 0; o < NOUT; ++o) {
        float lw = lin_w[f * NOUT + o];
        prep[f * NOUT + o] = sc * lw;
        red[o * FH + f]    = sh * lw;
    }
    __syncthreads();
    if (f < NOUT) {
        float s = lin_b[f];
        for (int i = 0; i < FH; ++i) s += red[f * FH + i];
        prep[3 * FH + f] = s;
    }
}

// ---------------------------------------------------------------------------
// K6: out[n][o] = sum_f agg[n][f] * wmod[f][o] + bias_out[o]
// ---------------------------------------------------------------------------
__global__ __launch_bounds__(256) void k_final(const unsigned int* __restrict__ agg2,
                                               const float* __restrict__ prep,
                                               float* __restrict__ out) {
    int n = blockIdx.x * 4 + (threadIdx.x >> 6);
    int lane = threadIdx.x & 63;
    int f0 = lane * 2, f1 = lane * 2 + 1;

    unsigned int v = agg2[(size_t)n * 64 + lane];
    float vx = bf16_lo(v), vy = bf16_hi(v);

    float o0 = vx * prep[f0 * NOUT + 0] + vy * prep[f1 * NOUT + 0];
    float o1 = vx * prep[f0 * NOUT + 1] + vy * prep[f1 * NOUT + 1];
    float o2 = vx * prep[f0 * NOUT + 2] + vy * prep[f1 * NOUT + 2];

#pragma unroll
    for (int off = 32; off > 0; off >>= 1) {
        o0 += __shfl_down(o0, off, 64);
        o1 += __shfl_down(o1, off, 64);
        o2 += __shfl_down(o2, off, 64);
    }
    if (lane == 0) {
        out[n * NOUT + 0] = o0 + prep[3 * FH + 0];
        out[n * NOUT + 1] = o1 + prep[3 * FH + 1];
        out[n * NOUT + 2] = o2 + prep[3 * FH + 2];
    }
}

// ---------------------------------------------------------------------------
extern "C" void kernel_launch(void* const* d_in, const int* in_sizes, int n_in,
                              void* d_out, int out_size, void* d_ws, size_t ws_size,
                              hipStream_t stream) {
    const float* x      = (const float*)d_in[0];
    const int*   ei     = (const int*)d_in[1];   // [2][NE] int32
    const float* ew     = (const float*)d_in[2];
    const float* conv_w = (const float*)d_in[3];
    const float* conv_b = (const float*)d_in[4];
    const float* gamma  = (const float*)d_in[5];
    const float* beta   = (const float*)d_in[6];
    const float* lin_w  = (const float*)d_in[7];
    const float* lin_b  = (const float*)d_in[8];
    float* out = (float*)d_out;
    float* ws  = (float*)d_ws;

    unsigned int* h2     = (unsigned int*)(ws + WS_H2);
    unsigned int* agg2   = (unsigned int*)(ws + WS_AGG2);
    unsigned int* bucket = (unsigned int*)(ws + WS_BUCKET);
    int*          cnt    = (int*)(ws + WS_CNT);
    float*        dinv   = ws + WS_DINV;
    float*        sums   = ws + WS_SUMS;
    float*        prep   = ws + WS_PREP;

    // ws is poisoned 0xAA before every launch — zero the accumulators.
    hipMemsetAsync(cnt,  0, (size_t)NN * sizeof(int), stream);
    hipMemsetAsync(sums, 0, 2 * FH * sizeof(float), stream);

    k_gemm_bucket<<<FUSED_BLKS, 256, 0, stream>>>(
        x, conv_w, h2, ei, ew, cnt, bucket);
    k_degdinv<<<NN / 4, 256, 0, stream>>>(bucket, cnt, dinv);
    k_gather <<<NN / 4, 256, 0, stream>>>(h2, dinv, bucket, cnt, conv_b, agg2);
    k_stats  <<<512,    256, 0, stream>>>(agg2, sums);
    k_prep   <<<1,      FH,  0, stream>>>(sums, gamma, beta, lin_w, lin_b, prep);
    k_final  <<<NN / 4, 256, 0, stream>>>(agg2, prep, out);
}